// Round 1
// baseline (1026.213 us; speedup 1.0000x reference)
//
#include <hip/hip_runtime.h>
#include <stdint.h>

// ---------------- types / helpers ----------------
using bf16x8 = __attribute__((ext_vector_type(8))) short;   // 8 x bf16 (4 VGPRs)
using f32x4  = __attribute__((ext_vector_type(4))) float;

__device__ __forceinline__ f32x4 mfma16(bf16x8 a, bf16x8 b, f32x4 c) {
  return __builtin_amdgcn_mfma_f32_16x16x32_bf16(a, b, c, 0, 0, 0);
}

__device__ __forceinline__ unsigned short f2b_rne(float f) {
  union { float f; unsigned u; } v; v.f = f;
  unsigned r = v.u + 0x7fffu + ((v.u >> 16) & 1u);
  return (unsigned short)(r >> 16);
}

__device__ __forceinline__ void gload16(const void* g, void* l) {
  __builtin_amdgcn_global_load_lds(
      (const __attribute__((address_space(1))) void*)g,
      (__attribute__((address_space(3))) void*)l, 16, 0, 0);
}

// ---------------- fp32 -> bf16 conversion ----------------
__global__ void f2b_kernel(const float* __restrict__ s, unsigned short* __restrict__ d, int n4) {
  int i = blockIdx.x * 256 + threadIdx.x;
  if (i >= n4) return;
  float4 v = reinterpret_cast<const float4*>(s)[i];
  ushort4 o;
  o.x = f2b_rne(v.x); o.y = f2b_rne(v.y); o.z = f2b_rne(v.z); o.w = f2b_rne(v.w);
  reinterpret_cast<ushort4*>(d)[i] = o;
}

// ---------------- trunk GEMM: C[16 x 256] = A[16xK] @ W[(col0..col0+256) x K]^T ----------------
// EPI: 0 = ybf = C+b ; 1 = ybf = gelu(C+b) ; 2 = h (f32+bf16) = C+b ;
//      3 = h = LN(h + C + b)*gam + bet ; 4 = h = h + C + b
// grid.x = 4096/16 = 256, grid.y = N/256. 256 threads (4 waves); wave w owns cols w*64..w*64+64.
template<int EPI>
__global__ __launch_bounds__(256) void gemm_trunk(
    const unsigned short* __restrict__ A, const unsigned short* __restrict__ W,
    const float* __restrict__ bias, float* __restrict__ hf,
    unsigned short* __restrict__ ybf, const float* __restrict__ gam,
    const float* __restrict__ bet, int K, int Nout) {
  // LDS: W tiles [2][256][32]bf16 at 0 (16384 each); A tiles [2][16][32]bf16 at 32768 (1024 each)
  __shared__ char sm[34816];
  __shared__ float red[2][4][16];
  const int tid = threadIdx.x, wid = tid >> 6, lane = tid & 63;
  const int g = lane >> 4, r = lane & 15;
  const int row0 = blockIdx.x << 4;
  const int col0 = blockIdx.y << 8;

  f32x4 acc[4] = {};
  const int nk = K >> 5;

  // prologue: stage k-slice 0 into buf 0 (17 x 1KB gload_lds: 16 W rows-of-16, 1 A)
  for (int i = wid; i < 17; i += 4) {
    if (i < 16) gload16(W + (size_t)(col0 + i * 16 + (lane >> 2)) * K + (lane & 3) * 8,
                        sm + i * 1024);
    else        gload16(A + (size_t)(row0 + (lane >> 2)) * K + (lane & 3) * 8,
                        sm + 32768);
  }
  for (int ks = 0; ks < nk; ++ks) {
    const int buf = ks & 1;
    __syncthreads();                     // drains vmcnt(0): buf is ready, other buf free
    if (ks + 1 < nk) {
      const int nb = buf ^ 1, k0 = (ks + 1) << 5;
      for (int i = wid; i < 17; i += 4) {
        if (i < 16) gload16(W + (size_t)(col0 + i * 16 + (lane >> 2)) * K + k0 + (lane & 3) * 8,
                            sm + nb * 16384 + i * 1024);
        else        gload16(A + (size_t)(row0 + (lane >> 2)) * K + k0 + (lane & 3) * 8,
                            sm + 32768 + nb * 1024);
      }
    }
    bf16x8 a = *reinterpret_cast<const bf16x8*>(sm + 32768 + buf * 1024 + r * 64 + g * 16);
#pragma unroll
    for (int n = 0; n < 4; ++n) {
      bf16x8 b = *reinterpret_cast<const bf16x8*>(sm + buf * 16384 + (wid * 64 + n * 16 + r) * 64 + g * 16);
      acc[n] = mfma16(a, b, acc[n]);
    }
  }

  // epilogue (C row = row0 + g*4 + j ; C col = col0 + wid*64 + n*16 + r)
  if (EPI == 0 || EPI == 1) {
#pragma unroll
    for (int n = 0; n < 4; ++n) {
      const int lc = wid * 64 + n * 16 + r;
      const float bv = bias[col0 + lc];
#pragma unroll
      for (int j = 0; j < 4; ++j) {
        const int row = row0 + g * 4 + j;
        float y = acc[n][j] + bv;
        if (EPI == 1) y = 0.5f * y * (1.f + erff(y * 0.70710678118654752f));
        ybf[(size_t)row * Nout + col0 + lc] = f2b_rne(y);
      }
    }
  } else if (EPI == 2 || EPI == 4) {
#pragma unroll
    for (int n = 0; n < 4; ++n) {
      const int lc = wid * 64 + n * 16 + r;
      const float bv = bias[lc];
#pragma unroll
      for (int j = 0; j < 4; ++j) {
        const int row = row0 + g * 4 + j;
        float y = acc[n][j] + bv;
        if (EPI == 4) y += hf[(size_t)row * 256 + lc];
        hf[(size_t)row * 256 + lc]  = y;
        ybf[(size_t)row * 256 + lc] = f2b_rne(y);
      }
    }
  } else {  // EPI == 3 : h = LN(h + C + bias)
    float xx[4][4];
    float sum[4] = {0.f, 0.f, 0.f, 0.f}, sq[4] = {0.f, 0.f, 0.f, 0.f};
#pragma unroll
    for (int n = 0; n < 4; ++n) {
      const int lc = wid * 64 + n * 16 + r;
      const float bv = bias[lc];
#pragma unroll
      for (int j = 0; j < 4; ++j) {
        float v = hf[(size_t)(row0 + g * 4 + j) * 256 + lc] + acc[n][j] + bv;
        xx[n][j] = v; sum[j] += v; sq[j] += v * v;
      }
    }
    // reduce across the 16 lanes of each quarter-wave group (this wave's 64 cols)
#pragma unroll
    for (int m = 1; m < 16; m <<= 1) {
#pragma unroll
      for (int j = 0; j < 4; ++j) {
        sum[j] += __shfl_xor(sum[j], m, 64);
        sq[j]  += __shfl_xor(sq[j],  m, 64);
      }
    }
    if (r == 0) {
#pragma unroll
      for (int j = 0; j < 4; ++j) { red[0][wid][g * 4 + j] = sum[j]; red[1][wid][g * 4 + j] = sq[j]; }
    }
    __syncthreads();
    float mu[4], rs[4];
#pragma unroll
    for (int j = 0; j < 4; ++j) {
      float ts = red[0][0][g * 4 + j] + red[0][1][g * 4 + j] + red[0][2][g * 4 + j] + red[0][3][g * 4 + j];
      float tq = red[1][0][g * 4 + j] + red[1][1][g * 4 + j] + red[1][2][g * 4 + j] + red[1][3][g * 4 + j];
      float mean = ts * (1.f / 256.f);
      mu[j] = mean;
      rs[j] = rsqrtf(tq * (1.f / 256.f) - mean * mean + 1e-5f);
    }
#pragma unroll
    for (int n = 0; n < 4; ++n) {
      const int lc = wid * 64 + n * 16 + r;
      const float gm = gam[lc], bb = bet[lc];
#pragma unroll
      for (int j = 0; j < 4; ++j) {
        const int row = row0 + g * 4 + j;
        float y = (xx[n][j] - mu[j]) * rs[j] * gm + bb;
        hf[(size_t)row * 256 + lc]  = y;
        ybf[(size_t)row * 256 + lc] = f2b_rne(y);
      }
    }
  }
}

// ---------------- phase D: fused per-token MLP ----------------
// grid (4096/64, 424), 256 threads (2x2 waves).
// C1[64][128] = h[64x256] @ W1[t]^T ; LN(128)+relu -> t1 bf16 ; C2[64][64] = t1 @ W2[t]^T ;
// out[b,t] = relu(C2 + b2) . W3[t] + b3[t]
__global__ __launch_bounds__(256) void phase_d(
    const unsigned short* __restrict__ hbf, const unsigned short* __restrict__ w1b,
    const float* __restrict__ b1, const float* __restrict__ lng, const float* __restrict__ lnb,
    const unsigned short* __restrict__ w2b, const float* __restrict__ b2,
    const float* __restrict__ w3, const float* __restrict__ b3,
    float* __restrict__ out) {
  // LDS: A stage [2][64][32]bf16 @0 (4096 ea), W1 stage [2][128][32]bf16 @8192 (8192 ea)
  //      (stage region reused as t1[64][136]bf16 @0 after GEMM1)
  //      c1[64][132]f32 @24576 (reused as z[64][68]f32 after LN)
  __shared__ char sm[58368];
  const int tid = threadIdx.x, wid = tid >> 6, lane = tid & 63;
  const int g = lane >> 4, r = lane & 15;
  const int wr = wid >> 1, wc = wid & 1;
  const int b0 = blockIdx.x << 6;
  const int t = blockIdx.y;
  const unsigned short* w1t = w1b + (size_t)t * 32768;

  f32x4 acc1[2][4] = {};

  for (int i = wid; i < 12; i += 4) {     // prologue stage, buf 0, k0 = 0
    if (i < 4) gload16(hbf + (size_t)(b0 + i * 16 + (lane >> 2)) * 256 + (lane & 3) * 8,
                       sm + i * 1024);
    else       gload16(w1t + (size_t)((i - 4) * 16 + (lane >> 2)) * 256 + (lane & 3) * 8,
                       sm + 8192 + (i - 4) * 1024);
  }
  for (int ks = 0; ks < 8; ++ks) {
    const int buf = ks & 1;
    __syncthreads();
    if (ks < 7) {
      const int nb = buf ^ 1, k0 = (ks + 1) << 5;
      for (int i = wid; i < 12; i += 4) {
        if (i < 4) gload16(hbf + (size_t)(b0 + i * 16 + (lane >> 2)) * 256 + k0 + (lane & 3) * 8,
                           sm + nb * 4096 + i * 1024);
        else       gload16(w1t + (size_t)((i - 4) * 16 + (lane >> 2)) * 256 + k0 + (lane & 3) * 8,
                           sm + 8192 + nb * 8192 + (i - 4) * 1024);
      }
    }
    bf16x8 a0 = *reinterpret_cast<const bf16x8*>(sm + buf * 4096 + (wr * 32 + r) * 64 + g * 16);
    bf16x8 a1 = *reinterpret_cast<const bf16x8*>(sm + buf * 4096 + (wr * 32 + 16 + r) * 64 + g * 16);
#pragma unroll
    for (int n = 0; n < 4; ++n) {
      bf16x8 b = *reinterpret_cast<const bf16x8*>(sm + 8192 + buf * 8192 + (wc * 64 + n * 16 + r) * 64 + g * 16);
      acc1[0][n] = mfma16(a0, b, acc1[0][n]);
      acc1[1][n] = mfma16(a1, b, acc1[1][n]);
    }
  }

  // C1 + bias -> LDS c1[64][132] (padded stride vs bank conflicts)
  float* c1 = reinterpret_cast<float*>(sm + 24576);
#pragma unroll
  for (int m = 0; m < 2; ++m)
#pragma unroll
    for (int n = 0; n < 4; ++n) {
      const int col = wc * 64 + n * 16 + r;
      const float bv = b1[t * 128 + col];
#pragma unroll
      for (int j = 0; j < 4; ++j)
        c1[(wr * 32 + m * 16 + g * 4 + j) * 132 + col] = acc1[m][n][j] + bv;
    }
  __syncthreads();   // c1 ready; stage region now dead -> safe to write t1

  // LN over 128 + relu -> t1 bf16 [64][136] at LDS 0 (4 threads per row)
  {
    const int row = tid >> 2, q = tid & 3;
    f32x4 xv[8];
    float s = 0.f, s2 = 0.f;
#pragma unroll
    for (int e = 0; e < 8; ++e) {
      xv[e] = *reinterpret_cast<const f32x4*>(&c1[row * 132 + q * 32 + e * 4]);
#pragma unroll
      for (int c = 0; c < 4; ++c) { s += xv[e][c]; s2 += xv[e][c] * xv[e][c]; }
    }
    s  += __shfl_xor(s, 1, 64);  s  += __shfl_xor(s, 2, 64);
    s2 += __shfl_xor(s2, 1, 64); s2 += __shfl_xor(s2, 2, 64);
    const float mean = s * (1.f / 128.f);
    const float rs = rsqrtf(s2 * (1.f / 128.f) - mean * mean + 1e-5f);
    unsigned short* t1 = reinterpret_cast<unsigned short*>(sm);
#pragma unroll
    for (int e = 0; e < 8; ++e) {
#pragma unroll
      for (int c = 0; c < 4; ++c) {
        const int col = q * 32 + e * 4 + c;
        float v = (xv[e][c] - mean) * rs * lng[t * 128 + col] + lnb[t * 128 + col];
        t1[row * 136 + col] = f2b_rne(fmaxf(v, 0.f));
      }
    }
  }
  __syncthreads();

  // GEMM2: C2[64][64] = t1[64x128] @ W2[t][64x128]^T  (W2 fragments straight from global/L2)
  f32x4 acc2[2][2] = {};
  const unsigned short* t1c = reinterpret_cast<const unsigned short*>(sm);
  const unsigned short* w2t = w2b + (size_t)t * 8192;
#pragma unroll
  for (int kk = 0; kk < 4; ++kk) {
    bf16x8 a0 = *reinterpret_cast<const bf16x8*>(&t1c[(wr * 32 + r) * 136 + kk * 32 + g * 8]);
    bf16x8 a1 = *reinterpret_cast<const bf16x8*>(&t1c[(wr * 32 + 16 + r) * 136 + kk * 32 + g * 8]);
#pragma unroll
    for (int n = 0; n < 2; ++n) {
      bf16x8 b = *reinterpret_cast<const bf16x8*>(&w2t[(wc * 32 + n * 16 + r) * 128 + kk * 32 + g * 8]);
      acc2[0][n] = mfma16(a0, b, acc2[0][n]);
      acc2[1][n] = mfma16(a1, b, acc2[1][n]);
    }
  }

  // relu(C2 + b2) -> z[64][68] f32 (c1 region, dead now)
  float* z = reinterpret_cast<float*>(sm + 24576);
#pragma unroll
  for (int m = 0; m < 2; ++m)
#pragma unroll
    for (int n = 0; n < 2; ++n) {
      const int col = wc * 32 + n * 16 + r;
      const float bv = b2[t * 64 + col];
#pragma unroll
      for (int j = 0; j < 4; ++j)
        z[(wr * 32 + m * 16 + g * 4 + j) * 68 + col] = fmaxf(acc2[m][n][j] + bv, 0.f);
    }
  __syncthreads();

  // out[b,t] = z[row] . w3[t] + b3[t]
  {
    const int row = tid >> 2, q = tid & 3;
    float s = 0.f;
#pragma unroll
    for (int e = 0; e < 16; ++e)
      s += z[row * 68 + q * 16 + e] * w3[t * 64 + q * 16 + e];
    s += __shfl_xor(s, 1, 64); s += __shfl_xor(s, 2, 64);
    if (q == 0) out[(size_t)(b0 + row) * 424 + t] = s + b3[t];
  }
}

// ---------------- host launch ----------------
extern "C" void kernel_launch(void* const* d_in, const int* in_sizes, int n_in,
                              void* d_out, int out_size, void* d_ws, size_t ws_size,
                              hipStream_t stream) {
  const float* x     = (const float*)d_in[0];
  const float* projW = (const float*)d_in[1];
  const float* projb = (const float*)d_in[2];
  const float* aiW   = (const float*)d_in[3];
  const float* aib   = (const float*)d_in[4];
  const float* aoW   = (const float*)d_in[5];
  const float* aob   = (const float*)d_in[6];
  const float* lng   = (const float*)d_in[7];
  const float* lnbp  = (const float*)d_in[8];
  const float* f1W   = (const float*)d_in[9];
  const float* f1b   = (const float*)d_in[10];
  const float* f2W   = (const float*)d_in[11];
  const float* f2bp  = (const float*)d_in[12];
  const float* ciW   = (const float*)d_in[13];
  const float* cib   = (const float*)d_in[14];
  const float* coW   = (const float*)d_in[15];
  const float* cob   = (const float*)d_in[16];
  const float* tpW1  = (const float*)d_in[17];
  const float* tpb1  = (const float*)d_in[18];
  const float* tplng = (const float*)d_in[19];
  const float* tplnb = (const float*)d_in[20];
  const float* tpW2  = (const float*)d_in[21];
  const float* tpb2  = (const float*)d_in[22];
  const float* tpW3  = (const float*)d_in[23];
  const float* tpb3  = (const float*)d_in[24];
  float* out = (float*)d_out;

  char* ws = (char*)d_ws;
  size_t off = 0;
  auto alloc = [&](size_t n) { char* p = ws + off; off = (off + n + 255) & ~(size_t)255; return p; };
  unsigned short* xb   = (unsigned short*)alloc(4096ull * 512 * 2);
  unsigned short* pWb  = (unsigned short*)alloc(256ull * 512 * 2);
  unsigned short* aiWb = (unsigned short*)alloc(6ull * 768 * 256 * 2);
  unsigned short* aoWb = (unsigned short*)alloc(6ull * 256 * 256 * 2);
  unsigned short* f1Wb = (unsigned short*)alloc(6ull * 1024 * 256 * 2);
  unsigned short* f2Wb = (unsigned short*)alloc(6ull * 256 * 1024 * 2);
  unsigned short* ciWb = (unsigned short*)alloc(768ull * 256 * 2);
  unsigned short* coWb = (unsigned short*)alloc(256ull * 256 * 2);
  unsigned short* W1b  = (unsigned short*)alloc(424ull * 128 * 256 * 2);
  unsigned short* W2b  = (unsigned short*)alloc(424ull * 64 * 128 * 2);
  float*          hf   = (float*)alloc(4096ull * 256 * 4);
  unsigned short* hbf  = (unsigned short*)alloc(4096ull * 256 * 2);
  unsigned short* vbf  = (unsigned short*)alloc(4096ull * 256 * 2);
  unsigned short* gbf  = (unsigned short*)alloc(4096ull * 1024 * 2);

  auto conv = [&](const float* s, unsigned short* d, size_t n) {
    int n4 = (int)(n >> 2);
    f2b_kernel<<<dim3((n4 + 255) / 256), dim3(256), 0, stream>>>(s, d, n4);
  };
  conv(x, xb, 4096ull * 512);
  conv(projW, pWb, 256ull * 512);
  conv(aiW, aiWb, 6ull * 768 * 256);
  conv(aoW, aoWb, 6ull * 256 * 256);
  conv(f1W, f1Wb, 6ull * 1024 * 256);
  conv(f2W, f2Wb, 6ull * 256 * 1024);
  conv(ciW, ciWb, 768ull * 256);
  conv(coW, coWb, 256ull * 256);
  conv(tpW1, W1b, 424ull * 128 * 256);
  conv(tpW2, W2b, 424ull * 64 * 128);

  dim3 blk(256);
  // proj: h = x @ proj_W(256x512)^T + b   (proj_W (4,64,512) flat == (256,512) row-major)
  gemm_trunk<2><<<dim3(256, 1), blk, 0, stream>>>(xb, pWb, projb, hf, hbf, nullptr, nullptr, 512, 256);
  for (int i = 0; i < 6; ++i) {
    // v = h @ Wv^T + bv   (Wv = attn_in_W[i] rows 512..767)
    gemm_trunk<0><<<dim3(256, 1), blk, 0, stream>>>(hbf, aiWb + ((size_t)i * 768 + 512) * 256,
                                                    aib + i * 768 + 512, nullptr, vbf, nullptr, nullptr, 256, 256);
    // h = LN(h + v @ Wo^T + bo)
    gemm_trunk<3><<<dim3(256, 1), blk, 0, stream>>>(vbf, aoWb + (size_t)i * 256 * 256, aob + i * 256,
                                                    hf, hbf, lng + i * 256, lnbp + i * 256, 256, 256);
    // g = gelu(h @ W1^T + b1)
    gemm_trunk<1><<<dim3(256, 4), blk, 0, stream>>>(hbf, f1Wb + (size_t)i * 1024 * 256, f1b + i * 1024,
                                                    nullptr, gbf, nullptr, nullptr, 256, 1024);
    // h = LN(h + g @ W2^T + b2)
    gemm_trunk<3><<<dim3(256, 1), blk, 0, stream>>>(gbf, f2Wb + (size_t)i * 256 * 1024, f2bp + i * 256,
                                                    hf, hbf, lng + i * 256, lnbp + i * 256, 1024, 256);
  }
  // cross: h = h + (h @ Wcv^T + bcv) @ Wco^T + bco
  gemm_trunk<0><<<dim3(256, 1), blk, 0, stream>>>(hbf, ciWb + 512ull * 256, cib + 512,
                                                  nullptr, vbf, nullptr, nullptr, 256, 256);
  gemm_trunk<4><<<dim3(256, 1), blk, 0, stream>>>(vbf, coWb, cob, hf, hbf, nullptr, nullptr, 256, 256);

  // phase D: fused per-token MLP -> out (4096 x 424)
  phase_d<<<dim3(64, 424), blk, 0, stream>>>(hbf, W1b, tpb1, tplng, tplnb, W2b, tpb2, tpW3, tpb3, out);
}

// Round 2
// 599.274 us; speedup vs baseline: 1.7124x; 1.7124x over previous
//
#include <hip/hip_runtime.h>
#include <stdint.h>

// ---------------- types / helpers ----------------
using bf16x8 = __attribute__((ext_vector_type(8))) short;   // 8 x bf16 (4 VGPRs)
using f32x4  = __attribute__((ext_vector_type(4))) float;

__device__ __forceinline__ f32x4 mfma16(bf16x8 a, bf16x8 b, f32x4 c) {
  return __builtin_amdgcn_mfma_f32_16x16x32_bf16(a, b, c, 0, 0, 0);
}

__device__ __forceinline__ unsigned short f2b_rne(float f) {
  union { float f; unsigned u; } v; v.f = f;
  unsigned r = v.u + 0x7fffu + ((v.u >> 16) & 1u);
  return (unsigned short)(r >> 16);
}

__device__ __forceinline__ void gload16(const void* g, void* l) {
  __builtin_amdgcn_global_load_lds(
      (const __attribute__((address_space(1))) void*)g,
      (__attribute__((address_space(3))) void*)l, 16, 0, 0);
}

// ---------------- fp32 -> bf16 conversion ----------------
__global__ void f2b_kernel(const float* __restrict__ s, unsigned short* __restrict__ d, int n4) {
  int i = blockIdx.x * 256 + threadIdx.x;
  if (i >= n4) return;
  float4 v = reinterpret_cast<const float4*>(s)[i];
  ushort4 o;
  o.x = f2b_rne(v.x); o.y = f2b_rne(v.y); o.z = f2b_rne(v.z); o.w = f2b_rne(v.w);
  reinterpret_cast<ushort4*>(d)[i] = o;
}

// ---------------- trunk GEMM: C[16 x 256] = A[16xK] @ W[(col0..col0+256) x K]^T ----------------
// EPI: 0 = ybf = C+b ; 1 = ybf = gelu(C+b) ; 2 = h (f32+bf16) = C+b ;
//      3 = h = LN(h + C + b)*gam + bet ; 4 = h = h + C + b
template<int EPI>
__global__ __launch_bounds__(256) void gemm_trunk(
    const unsigned short* __restrict__ A, const unsigned short* __restrict__ W,
    const float* __restrict__ bias, float* __restrict__ hf,
    unsigned short* __restrict__ ybf, const float* __restrict__ gam,
    const float* __restrict__ bet, int K, int Nout) {
  __shared__ char sm[34816];
  __shared__ float red[2][4][16];
  const int tid = threadIdx.x, wid = tid >> 6, lane = tid & 63;
  const int g = lane >> 4, r = lane & 15;
  const int row0 = blockIdx.x << 4;
  const int col0 = blockIdx.y << 8;

  f32x4 acc[4] = {};
  const int nk = K >> 5;

  for (int i = wid; i < 17; i += 4) {
    if (i < 16) gload16(W + (size_t)(col0 + i * 16 + (lane >> 2)) * K + (lane & 3) * 8,
                        sm + i * 1024);
    else        gload16(A + (size_t)(row0 + (lane >> 2)) * K + (lane & 3) * 8,
                        sm + 32768);
  }
  for (int ks = 0; ks < nk; ++ks) {
    const int buf = ks & 1;
    __syncthreads();
    if (ks + 1 < nk) {
      const int nb = buf ^ 1, k0 = (ks + 1) << 5;
      for (int i = wid; i < 17; i += 4) {
        if (i < 16) gload16(W + (size_t)(col0 + i * 16 + (lane >> 2)) * K + k0 + (lane & 3) * 8,
                            sm + nb * 16384 + i * 1024);
        else        gload16(A + (size_t)(row0 + (lane >> 2)) * K + k0 + (lane & 3) * 8,
                            sm + 32768 + nb * 1024);
      }
    }
    bf16x8 a = *reinterpret_cast<const bf16x8*>(sm + 32768 + buf * 1024 + r * 64 + g * 16);
#pragma unroll
    for (int n = 0; n < 4; ++n) {
      bf16x8 b = *reinterpret_cast<const bf16x8*>(sm + buf * 16384 + (wid * 64 + n * 16 + r) * 64 + g * 16);
      acc[n] = mfma16(a, b, acc[n]);
    }
  }

  if (EPI == 0 || EPI == 1) {
#pragma unroll
    for (int n = 0; n < 4; ++n) {
      const int lc = wid * 64 + n * 16 + r;
      const float bv = bias[col0 + lc];
#pragma unroll
      for (int j = 0; j < 4; ++j) {
        const int row = row0 + g * 4 + j;
        float y = acc[n][j] + bv;
        if (EPI == 1) y = 0.5f * y * (1.f + erff(y * 0.70710678118654752f));
        ybf[(size_t)row * Nout + col0 + lc] = f2b_rne(y);
      }
    }
  } else if (EPI == 2 || EPI == 4) {
#pragma unroll
    for (int n = 0; n < 4; ++n) {
      const int lc = wid * 64 + n * 16 + r;
      const float bv = bias[lc];
#pragma unroll
      for (int j = 0; j < 4; ++j) {
        const int row = row0 + g * 4 + j;
        float y = acc[n][j] + bv;
        if (EPI == 4) y += hf[(size_t)row * 256 + lc];
        hf[(size_t)row * 256 + lc]  = y;
        ybf[(size_t)row * 256 + lc] = f2b_rne(y);
      }
    }
  } else {
    float xx[4][4];
    float sum[4] = {0.f, 0.f, 0.f, 0.f}, sq[4] = {0.f, 0.f, 0.f, 0.f};
#pragma unroll
    for (int n = 0; n < 4; ++n) {
      const int lc = wid * 64 + n * 16 + r;
      const float bv = bias[lc];
#pragma unroll
      for (int j = 0; j < 4; ++j) {
        float v = hf[(size_t)(row0 + g * 4 + j) * 256 + lc] + acc[n][j] + bv;
        xx[n][j] = v; sum[j] += v; sq[j] += v * v;
      }
    }
#pragma unroll
    for (int m = 1; m < 16; m <<= 1) {
#pragma unroll
      for (int j = 0; j < 4; ++j) {
        sum[j] += __shfl_xor(sum[j], m, 64);
        sq[j]  += __shfl_xor(sq[j],  m, 64);
      }
    }
    if (r == 0) {
#pragma unroll
      for (int j = 0; j < 4; ++j) { red[0][wid][g * 4 + j] = sum[j]; red[1][wid][g * 4 + j] = sq[j]; }
    }
    __syncthreads();
    float mu[4], rs[4];
#pragma unroll
    for (int j = 0; j < 4; ++j) {
      float ts = red[0][0][g * 4 + j] + red[0][1][g * 4 + j] + red[0][2][g * 4 + j] + red[0][3][g * 4 + j];
      float tq = red[1][0][g * 4 + j] + red[1][1][g * 4 + j] + red[1][2][g * 4 + j] + red[1][3][g * 4 + j];
      float mean = ts * (1.f / 256.f);
      mu[j] = mean;
      rs[j] = rsqrtf(tq * (1.f / 256.f) - mean * mean + 1e-5f);
    }
#pragma unroll
    for (int n = 0; n < 4; ++n) {
      const int lc = wid * 64 + n * 16 + r;
      const float gm = gam[lc], bb = bet[lc];
#pragma unroll
      for (int j = 0; j < 4; ++j) {
        const int row = row0 + g * 4 + j;
        float y = (xx[n][j] - mu[j]) * rs[j] * gm + bb;
        hf[(size_t)row * 256 + lc]  = y;
        ybf[(size_t)row * 256 + lc] = f2b_rne(y);
      }
    }
  }
}

// ---------------- phase D v2: weight-stationary, barrier-free per-wave tiles ----------------
// Grid: (blocks_per_token=4, 424). 512 threads = 8 waves; each wave owns 64 batch rows/tile,
// block does 2 tiles of 512 rows => 1024 rows/block.
// LDS: W1s[128][256]bf16 swizzled @0 (64KB) | W2s[64][128]bf16 swizzled @65536 (16KB)
//      consts 512 f32 @81920 (b1|g|beta|b2|w3) | t1 per-wave 8KB @83968 (32 rows x 128 cols bf16)
// Swapped MFMA: D[c][b] = mfma(A=W1frag, B=hfrag). Lane: b = lane&15 (r), c = (lane>>4)*4+j (+16*cf).
// LN over c is in-lane(32 vals) + shfl_xor(16,32). t1 write = contiguous 4 cols -> b64 stores.
// GEMM2: D2[c2][b] = mfma(A=W2frag, B=t1frag); epilogue dot with w3, reduce over hi, store out.
__global__ __launch_bounds__(512, 2) void phase_d2(
    const unsigned short* __restrict__ hbf, const unsigned short* __restrict__ w1b,
    const float* __restrict__ b1, const float* __restrict__ lng, const float* __restrict__ lnb,
    const unsigned short* __restrict__ w2b, const float* __restrict__ b2,
    const float* __restrict__ w3, const float* __restrict__ b3,
    float* __restrict__ out) {
  __shared__ char sm[149504];
  const int tid = threadIdx.x, wid = tid >> 6, lane = tid & 63;
  const int r = lane & 15, hi = lane >> 4;
  const int sw = (r & 7) << 4;
  const int t = blockIdx.y;

  // ---- prologue: stage W1 (swizzled), W2 (swizzled), consts ----
  const unsigned short* w1t = w1b + (size_t)t * 32768;   // [128][256]
  const unsigned short* w2t = w2b + (size_t)t * 8192;    // [64][128]
#pragma unroll
  for (int i = 0; i < 8; ++i) {            // W1: 4096 16B chunks
    const int id = tid + i * 512;
    const int c = id >> 5, s = id & 31;
    bf16x8 v = *reinterpret_cast<const bf16x8*>(w1t + c * 256 + s * 8);
    *reinterpret_cast<bf16x8*>(sm + c * 512 + ((s * 16) ^ ((c & 7) << 4))) = v;
  }
#pragma unroll
  for (int i = 0; i < 2; ++i) {            // W2: 1024 16B chunks
    const int id = tid + i * 512;
    const int c = id >> 4, s = id & 15;
    bf16x8 v = *reinterpret_cast<const bf16x8*>(w2t + c * 128 + s * 8);
    *reinterpret_cast<bf16x8*>(sm + 65536 + c * 256 + ((s * 16) ^ ((c & 7) << 4))) = v;
  }
  {
    float v;
    if (tid < 128)      v = b1 [t * 128 + tid];
    else if (tid < 256) v = lng[t * 128 + tid - 128];
    else if (tid < 384) v = lnb[t * 128 + tid - 256];
    else if (tid < 448) v = b2 [t * 64  + tid - 384];
    else                v = w3 [t * 64  + tid - 448];
    reinterpret_cast<float*>(sm + 81920)[tid] = v;
  }
  __syncthreads();

  const float* cb1 = reinterpret_cast<const float*>(sm + 81920);
  const float* cg  = cb1 + 128;
  const float* cbe = cb1 + 256;
  const float* cb2 = cb1 + 384;
  const float* cw3 = cb1 + 448;
  char* t1w = sm + 83968 + wid * 8192;
  const float b3t = b3[t];
  const int token_b0 = blockIdx.x * 1024;

  for (int tile = 0; tile < 2; ++tile) {
    const int B0 = token_b0 + tile * 512 + wid * 64;   // this wave's 64 rows

    // ---- GEMM1: acc1[cf][bf] = W1 @ h^T  (swapped) ----
    f32x4 acc1[8][4] = {};
    bf16x8 bc[4], bn[4];
#pragma unroll
    for (int bf = 0; bf < 4; ++bf)
      bc[bf] = *reinterpret_cast<const bf16x8*>(hbf + (size_t)(B0 + bf * 16 + r) * 256 + hi * 8);
#pragma unroll
    for (int ks = 0; ks < 8; ++ks) {
      bf16x8 a[8];
#pragma unroll
      for (int cf = 0; cf < 8; ++cf)
        a[cf] = *reinterpret_cast<const bf16x8*>(sm + (cf * 16 + r) * 512 + ((ks * 64 + hi * 16) ^ sw));
      if (ks < 7) {
#pragma unroll
        for (int bf = 0; bf < 4; ++bf)
          bn[bf] = *reinterpret_cast<const bf16x8*>(hbf + (size_t)(B0 + bf * 16 + r) * 256 + (ks + 1) * 32 + hi * 8);
      }
#pragma unroll
      for (int cf = 0; cf < 8; ++cf)
#pragma unroll
        for (int bf = 0; bf < 4; ++bf)
          acc1[cf][bf] = mfma16(a[cf], bc[bf], acc1[cf][bf]);
#pragma unroll
      for (int bf = 0; bf < 4; ++bf) bc[bf] = bn[bf];
    }

    // ---- + b1 ----
#pragma unroll
    for (int cf = 0; cf < 8; ++cf) {
      f32x4 b1v = *reinterpret_cast<const f32x4*>(cb1 + cf * 16 + hi * 4);
#pragma unroll
      for (int bf = 0; bf < 4; ++bf) acc1[cf][bf] += b1v;
    }

    // ---- LN pass 1: mean / rstd per b-row (in-lane 32 vals + shfl over hi) ----
    float mu[4], rsd[4];
#pragma unroll
    for (int bf = 0; bf < 4; ++bf) {
      float s = 0.f, s2 = 0.f;
#pragma unroll
      for (int cf = 0; cf < 8; ++cf)
#pragma unroll
        for (int j = 0; j < 4; ++j) { float v = acc1[cf][bf][j]; s += v; s2 += v * v; }
      s  += __shfl_xor(s, 16, 64);  s  += __shfl_xor(s, 32, 64);
      s2 += __shfl_xor(s2, 16, 64); s2 += __shfl_xor(s2, 32, 64);
      const float m = s * (1.f / 128.f);
      mu[bf] = m;
      rsd[bf] = rsqrtf(s2 * (1.f / 128.f) - m * m + 1e-5f);
    }

    f32x4 acc2[4][4] = {};
#pragma unroll
    for (int half = 0; half < 2; ++half) {
      // ---- LN pass 2 + relu + bf16 pack -> per-wave t1 (32 rows x 128 cols) ----
#pragma unroll
      for (int cf = 0; cf < 8; ++cf) {
        f32x4 gv = *reinterpret_cast<const f32x4*>(cg  + cf * 16 + hi * 4);
        f32x4 bv = *reinterpret_cast<const f32x4*>(cbe + cf * 16 + hi * 4);
#pragma unroll
        for (int bl = 0; bl < 2; ++bl) {
          const int bf = half * 2 + bl;
          unsigned o01, o23;
          {
            float y0 = fmaxf((acc1[cf][bf][0] - mu[bf]) * rsd[bf] * gv[0] + bv[0], 0.f);
            float y1 = fmaxf((acc1[cf][bf][1] - mu[bf]) * rsd[bf] * gv[1] + bv[1], 0.f);
            float y2 = fmaxf((acc1[cf][bf][2] - mu[bf]) * rsd[bf] * gv[2] + bv[2], 0.f);
            float y3 = fmaxf((acc1[cf][bf][3] - mu[bf]) * rsd[bf] * gv[3] + bv[3], 0.f);
            o01 = (unsigned)f2b_rne(y0) | ((unsigned)f2b_rne(y1) << 16);
            o23 = (unsigned)f2b_rne(y2) | ((unsigned)f2b_rne(y3) << 16);
          }
          uint2 pk; pk.x = o01; pk.y = o23;
          *reinterpret_cast<uint2*>(t1w + (bl * 16 + r) * 256 + ((cf * 32 + hi * 8) ^ sw)) = pk;
        }
      }
      // ---- GEMM2 half: acc2[cf2][half*2+bl] += W2 @ t1^T ----
#pragma unroll
      for (int ks = 0; ks < 4; ++ks) {
        bf16x8 a2[4];
#pragma unroll
        for (int cf2 = 0; cf2 < 4; ++cf2)
          a2[cf2] = *reinterpret_cast<const bf16x8*>(sm + 65536 + (cf2 * 16 + r) * 256 + ((ks * 64 + hi * 16) ^ sw));
#pragma unroll
        for (int bl = 0; bl < 2; ++bl) {
          bf16x8 bb = *reinterpret_cast<const bf16x8*>(t1w + (bl * 16 + r) * 256 + ((ks * 64 + hi * 16) ^ sw));
#pragma unroll
          for (int cf2 = 0; cf2 < 4; ++cf2)
            acc2[cf2][half * 2 + bl] = mfma16(a2[cf2], bb, acc2[cf2][half * 2 + bl]);
        }
      }
    }

    // ---- epilogue: out[b,t] = relu(acc2 + b2) . w3 + b3 ----
    float s[4] = {0.f, 0.f, 0.f, 0.f};
#pragma unroll
    for (int cf2 = 0; cf2 < 4; ++cf2) {
      f32x4 b2v = *reinterpret_cast<const f32x4*>(cb2 + cf2 * 16 + hi * 4);
      f32x4 w3v = *reinterpret_cast<const f32x4*>(cw3 + cf2 * 16 + hi * 4);
#pragma unroll
      for (int bf = 0; bf < 4; ++bf)
#pragma unroll
        for (int j = 0; j < 4; ++j)
          s[bf] += fmaxf(acc2[cf2][bf][j] + b2v[j], 0.f) * w3v[j];
    }
#pragma unroll
    for (int bf = 0; bf < 4; ++bf) {
      s[bf] += __shfl_xor(s[bf], 16, 64);
      s[bf] += __shfl_xor(s[bf], 32, 64);
      if (hi == 0) out[(size_t)(B0 + bf * 16 + r) * 424 + t] = s[bf] + b3t;
    }
  }
}

// ---------------- host launch ----------------
extern "C" void kernel_launch(void* const* d_in, const int* in_sizes, int n_in,
                              void* d_out, int out_size, void* d_ws, size_t ws_size,
                              hipStream_t stream) {
  const float* x     = (const float*)d_in[0];
  const float* projW = (const float*)d_in[1];
  const float* projb = (const float*)d_in[2];
  const float* aiW   = (const float*)d_in[3];
  const float* aib   = (const float*)d_in[4];
  const float* aoW   = (const float*)d_in[5];
  const float* aob   = (const float*)d_in[6];
  const float* lng   = (const float*)d_in[7];
  const float* lnbp  = (const float*)d_in[8];
  const float* f1W   = (const float*)d_in[9];
  const float* f1b   = (const float*)d_in[10];
  const float* f2W   = (const float*)d_in[11];
  const float* f2bp  = (const float*)d_in[12];
  const float* ciW   = (const float*)d_in[13];
  const float* cib   = (const float*)d_in[14];
  const float* coW   = (const float*)d_in[15];
  const float* cob   = (const float*)d_in[16];
  const float* tpW1  = (const float*)d_in[17];
  const float* tpb1  = (const float*)d_in[18];
  const float* tplng = (const float*)d_in[19];
  const float* tplnb = (const float*)d_in[20];
  const float* tpW2  = (const float*)d_in[21];
  const float* tpb2  = (const float*)d_in[22];
  const float* tpW3  = (const float*)d_in[23];
  const float* tpb3  = (const float*)d_in[24];
  float* out = (float*)d_out;

  char* ws = (char*)d_ws;
  size_t off = 0;
  auto alloc = [&](size_t n) { char* p = ws + off; off = (off + n + 255) & ~(size_t)255; return p; };
  unsigned short* xb   = (unsigned short*)alloc(4096ull * 512 * 2);
  unsigned short* pWb  = (unsigned short*)alloc(256ull * 512 * 2);
  unsigned short* aiWb = (unsigned short*)alloc(6ull * 768 * 256 * 2);
  unsigned short* aoWb = (unsigned short*)alloc(6ull * 256 * 256 * 2);
  unsigned short* f1Wb = (unsigned short*)alloc(6ull * 1024 * 256 * 2);
  unsigned short* f2Wb = (unsigned short*)alloc(6ull * 256 * 1024 * 2);
  unsigned short* ciWb = (unsigned short*)alloc(768ull * 256 * 2);
  unsigned short* coWb = (unsigned short*)alloc(256ull * 256 * 2);
  unsigned short* W1b  = (unsigned short*)alloc(424ull * 128 * 256 * 2);
  unsigned short* W2b  = (unsigned short*)alloc(424ull * 64 * 128 * 2);
  float*          hf   = (float*)alloc(4096ull * 256 * 4);
  unsigned short* hbf  = (unsigned short*)alloc(4096ull * 256 * 2);
  unsigned short* vbf  = (unsigned short*)alloc(4096ull * 256 * 2);
  unsigned short* gbf  = (unsigned short*)alloc(4096ull * 1024 * 2);

  auto conv = [&](const float* s, unsigned short* d, size_t n) {
    int n4 = (int)(n >> 2);
    f2b_kernel<<<dim3((n4 + 255) / 256), dim3(256), 0, stream>>>(s, d, n4);
  };
  conv(x, xb, 4096ull * 512);
  conv(projW, pWb, 256ull * 512);
  conv(aiW, aiWb, 6ull * 768 * 256);
  conv(aoW, aoWb, 6ull * 256 * 256);
  conv(f1W, f1Wb, 6ull * 1024 * 256);
  conv(f2W, f2Wb, 6ull * 256 * 1024);
  conv(ciW, ciWb, 768ull * 256);
  conv(coW, coWb, 256ull * 256);
  conv(tpW1, W1b, 424ull * 128 * 256);
  conv(tpW2, W2b, 424ull * 64 * 128);

  dim3 blk(256);
  gemm_trunk<2><<<dim3(256, 1), blk, 0, stream>>>(xb, pWb, projb, hf, hbf, nullptr, nullptr, 512, 256);
  for (int i = 0; i < 6; ++i) {
    gemm_trunk<0><<<dim3(256, 1), blk, 0, stream>>>(hbf, aiWb + ((size_t)i * 768 + 512) * 256,
                                                    aib + i * 768 + 512, nullptr, vbf, nullptr, nullptr, 256, 256);
    gemm_trunk<3><<<dim3(256, 1), blk, 0, stream>>>(vbf, aoWb + (size_t)i * 256 * 256, aob + i * 256,
                                                    hf, hbf, lng + i * 256, lnbp + i * 256, 256, 256);
    gemm_trunk<1><<<dim3(256, 4), blk, 0, stream>>>(hbf, f1Wb + (size_t)i * 1024 * 256, f1b + i * 1024,
                                                    nullptr, gbf, nullptr, nullptr, 256, 1024);
    gemm_trunk<3><<<dim3(256, 1), blk, 0, stream>>>(gbf, f2Wb + (size_t)i * 256 * 1024, f2bp + i * 256,
                                                    hf, hbf, lng + i * 256, lnbp + i * 256, 1024, 256);
  }
  gemm_trunk<0><<<dim3(256, 1), blk, 0, stream>>>(hbf, ciWb + 512ull * 256, cib + 512,
                                                  nullptr, vbf, nullptr, nullptr, 256, 256);
  gemm_trunk<4><<<dim3(256, 1), blk, 0, stream>>>(vbf, coWb, cob, hf, hbf, nullptr, nullptr, 256, 256);

  // phase D v2: (4 blocks per token) x 424 tokens, 512 threads
  phase_d2<<<dim3(4, 424), dim3(512), 0, stream>>>(hbf, W1b, tpb1, tplng, tplnb, W2b, tpb2, tpW3, tpb3, out);
}